// Round 14
// baseline (290.672 us; speedup 1.0000x reference)
//
#include <hip/hip_runtime.h>
#include <hip/hip_bf16.h>
#include <stdint.h>

#define M_DIM 8192   // B*S
#define K_DIM 4096   // IN
#define N_DIM 4096   // OUT
#define NPIECE (K_DIM / 32)   // 128 K-pieces of 32

#define DQ_BLOCKS 8192    // N*(K/2)/4/256
#define CVT_BLOCKS 16384  // M*K/8/256

typedef __bf16 bf16x8v __attribute__((ext_vector_type(8)));
typedef float f32x4 __attribute__((ext_vector_type(4)));

__device__ __forceinline__ unsigned short f2bf(float f) {
    unsigned int u = __builtin_bit_cast(unsigned int, f);
    u += 0x7FFFu + ((u >> 16) & 1u);   // round-to-nearest-even
    return (unsigned short)(u >> 16);
}

// ---------- prep: blocks [0,DQ_BLOCKS) dequant qweight -> Wb; rest cvt x -> Xb
__global__ void k_prep(const int4* __restrict__ qw4,
                       const float* __restrict__ scales,
                       const float* __restrict__ lut,
                       uint4* __restrict__ wb4,
                       const float4* __restrict__ x4,
                       uint4* __restrict__ xb4) {
    if (blockIdx.x < DQ_BLOCKS) {
        __shared__ float sl[16];
        if (threadIdx.x < 16) sl[threadIdx.x] = lut[threadIdx.x];
        __syncthreads();
        int t = blockIdx.x * blockDim.x + threadIdx.x;   // N*(K/2)/4 threads
        int4 q = qw4[t];
        int o = t >> 9;                   // row (512 int4 per row)
        int col0 = (t & 511) << 3;        // first of 8 output cols
        float s = scales[(o << 5) + (col0 >> 7)];   // GS=128
        int v[4] = {q.x, q.y, q.z, q.w};
        unsigned int pk[4];
#pragma unroll
        for (int j = 0; j < 4; ++j) {
            float w0 = sl[v[j] & 15] * s;          // low nibble first
            float w1 = sl[(v[j] >> 4) & 15] * s;
            pk[j] = (unsigned int)f2bf(w0) | ((unsigned int)f2bf(w1) << 16);
        }
        uint4 rr; rr.x = pk[0]; rr.y = pk[1]; rr.z = pk[2]; rr.w = pk[3];
        wb4[t] = rr;
    } else {
        int t = (blockIdx.x - DQ_BLOCKS) * blockDim.x + threadIdx.x;   // M*K/8 threads
        float4 a = x4[2 * t], b = x4[2 * t + 1];
        uint4 o;
        o.x = (unsigned int)f2bf(a.x) | ((unsigned int)f2bf(a.y) << 16);
        o.y = (unsigned int)f2bf(a.z) | ((unsigned int)f2bf(a.w) << 16);
        o.z = (unsigned int)f2bf(b.x) | ((unsigned int)f2bf(b.y) << 16);
        o.w = (unsigned int)f2bf(b.z) | ((unsigned int)f2bf(b.w) << 16);
        xb4[t] = o;
    }
}

#define GLL16(SRC, DST)                                                              \
    __builtin_amdgcn_global_load_lds((__attribute__((address_space(1))) void*)(SRC), \
                                     (__attribute__((address_space(3))) void*)(DST), \
                                     16, 0, 0)

// ---------- GEMM: C[M][N] = Xb[M][K] * Wb[N][K]^T + bias
// Round-4 structure with FIVE 32KB LDS slots (160 KiB) and TWO pieces per sync
// epoch: body (P,P+1) reads slots {P,P+1,P+2}%5, stages {P+3,P+4}%5 (disjoint),
// ONE vmcnt(0)+barrier per body (64 barriers total vs 128). Reg-fragment
// pipeline, read addressing, swizzle, epilogue identical to the verified code.
__global__ __launch_bounds__(512, 1) void k_gemm(const __hip_bfloat16* __restrict__ A,
                                                 const __hip_bfloat16* __restrict__ Bw,
                                                 const float* __restrict__ bias,
                                                 float* __restrict__ C) {
    // slot: A piece [256 rows][32 K] bf16 (16KB) then B piece (16KB)
    __shared__ __align__(16) char lds[5][32768];   // 160 KiB

    const int tid  = threadIdx.x;
    const int lane = tid & 63;
    const int wave = tid >> 6;
    const int wm = wave >> 2;      // 0..1 -> M half
    const int wn = wave & 3;       // 0..3 -> N quarter
    const int bm = blockIdx.y, bn = blockIdx.x;

    f32x4 acc[8][4];
    const f32x4 z = {0.f, 0.f, 0.f, 0.f};
#pragma unroll
    for (int i = 0; i < 8; ++i)
#pragma unroll
        for (int j = 0; j < 4; ++j) acc[i][j] = z;

    // ---- staging addresses (pre-swizzled per-lane global source, linear LDS dest)
    const int trow = tid >> 2;                 // 0..127
    const int sg   = (tid & 3) ^ ((trow >> 1) & 3);   // swizzled source granule
    const char* aSrc = (const char*)A  + ((size_t)(bm * 256 + trow) * K_DIM) * 2 + sg * 16;
    const char* bSrc = (const char*)Bw + ((size_t)(bn * 256 + trow) * K_DIM) * 2 + sg * 16;
    const size_t hop = (size_t)128 * K_DIM * 2;   // +128 rows (second issue)
    const int woff = wave * 1024;                 // wave-uniform LDS dest base offset

    // ---- ds_read addresses (swizzled, verified zero-conflict)
    const int r   = lane & 15;
    const int kq  = lane >> 4;                  // K granule wanted
    const int gsw = kq ^ ((r >> 1) & 3);        // swizzled granule
    const int aOff = (wm * 128 + r) * 64 + gsw * 16;           // + m*1024
    const int bOff = 16384 + (wn * 64 + r) * 64 + gsw * 16;    // + n*1024

    bf16x8v aC[4], aN[4], bX[4], bY[4];

    // slot index mod 5 (compile-time P in all uses)
#define SLOT(P) ((const char*)&lds[0][0] + (size_t)((P) % 5) * 32768)
#define SLOTW(P) ((char*)&lds[0][0] + (size_t)((P) % 5) * 32768)

#define STAGE_A(P)                                                           \
    do {                                                                     \
        char* d_ = SLOTW(P);                                                 \
        const size_t ko_ = (size_t)(P) * 64;                                 \
        GLL16(aSrc + ko_,       d_ + 0    + woff);                           \
        GLL16(aSrc + hop + ko_, d_ + 8192 + woff);                           \
    } while (0)
#define STAGE_B(P)                                                           \
    do {                                                                     \
        char* d_ = SLOTW(P);                                                 \
        const size_t ko_ = (size_t)(P) * 64;                                 \
        GLL16(bSrc + ko_,       d_ + 16384 + woff);                          \
        GLL16(bSrc + hop + ko_, d_ + 24576 + woff);                          \
    } while (0)

    // Half of the round-4 piece body (no trailing sync). BCUR/BNXT as before.
#define PIECE_CORE(P, BCUR, BNXT, GLLON, RDNEXT)                                                       \
    do {                                                                                               \
        const char* slC_ = SLOT(P);                                                                    \
        const char* slN_ = SLOT((P) + 1);                                                              \
        /* HP0: reads A4-7(P); stage(P+3); MFMA m0-3 on prior-loaded regs */                           \
        _Pragma("unroll") for (int m = 0; m < 4; ++m)                                                  \
            aN[m] = *(const bf16x8v*)(slC_ + aOff + (m + 4) * 1024);                                   \
        if (GLLON) { STAGE_A((P) + 3); STAGE_B((P) + 3); }                                             \
        asm volatile("" ::: "memory");                                                                 \
        __builtin_amdgcn_s_setprio(1);                                                                 \
        _Pragma("unroll") for (int m = 0; m < 4; ++m)                                                  \
            _Pragma("unroll") for (int n = 0; n < 4; ++n)                                              \
                acc[m][n] = __builtin_amdgcn_mfma_f32_16x16x32_bf16(aC[m], BCUR[n], acc[m][n], 0, 0, 0); \
        __builtin_amdgcn_s_setprio(0);                                                                 \
        /* HP1: reads A0-3(P+1)->aC, B(P+1)->BNXT; MFMA m4-7 */                                        \
        if (RDNEXT) {                                                                                  \
            _Pragma("unroll") for (int m = 0; m < 4; ++m)                                              \
                aC[m] = *(const bf16x8v*)(slN_ + aOff + m * 1024);                                     \
            _Pragma("unroll") for (int n = 0; n < 4; ++n)                                              \
                BNXT[n] = *(const bf16x8v*)(slN_ + bOff + n * 1024);                                   \
        }                                                                                              \
        asm volatile("" ::: "memory");                                                                 \
        __builtin_amdgcn_s_setprio(1);                                                                 \
        _Pragma("unroll") for (int m = 0; m < 4; ++m)                                                  \
            _Pragma("unroll") for (int n = 0; n < 4; ++n)                                              \
                acc[m + 4][n] =                                                                        \
                    __builtin_amdgcn_mfma_f32_16x16x32_bf16(aN[m], BCUR[n], acc[m + 4][n], 0, 0, 0);   \
        __builtin_amdgcn_s_setprio(0);                                                                 \
    } while (0)

#define SYNC(WAITSTR)                                                        \
    do {                                                                     \
        asm volatile(WAITSTR ::: "memory");                                  \
        __builtin_amdgcn_s_barrier();                                        \
        asm volatile("" ::: "memory");                                       \
    } while (0)

    // ---- prologue: stage pieces 0,1,2 (12 loads); drain all; preload piece-0 regs
    STAGE_A(0); STAGE_B(0);
    STAGE_A(1); STAGE_B(1);
    STAGE_A(2); STAGE_B(2);
    SYNC("s_waitcnt vmcnt(0)");
#pragma unroll
    for (int m = 0; m < 4; ++m)
        aC[m] = *(const bf16x8v*)((const char*)&lds[0][0] + aOff + m * 1024);
#pragma unroll
    for (int n = 0; n < 4; ++n)
        bX[n] = *(const bf16x8v*)((const char*)&lds[0][0] + bOff + n * 1024);

    // ---- main loop: bodies of 2 pieces, one vmcnt(0)+barrier per body.
    // Body (p,p+1): reads slots {p,p+1,p+2}%5, stages {p+3,p+4}%5 (disjoint mod 5).
    for (int p = 0; p < NPIECE - 4; p += 2) {
        PIECE_CORE(p,     bX, bY, 1, 1);
        PIECE_CORE(p + 1, bY, bX, 1, 1);
        SYNC("s_waitcnt vmcnt(0)");
    }
    // ---- tail: body (124,125) stages only piece 127; body (126,127) drains
    PIECE_CORE(124, bX, bY, 1, 1);   // stages 127
    PIECE_CORE(125, bY, bX, 0, 1);
    SYNC("s_waitcnt vmcnt(0)");
    PIECE_CORE(126, bX, bY, 0, 1);
    PIECE_CORE(127, bY, bX, 0, 0);

#undef PIECE_CORE
#undef SYNC
#undef STAGE_A
#undef STAGE_B
#undef SLOT
#undef SLOTW

    // ---- epilogue: C/D layout col=lane&15, row=(lane>>4)*4+j
    const int q   = lane >> 4;
    const int gr0 = bm * 256 + wm * 128;
    const int gc0 = bn * 256 + wn * 64 + r;
    float bv[4];
#pragma unroll
    for (int n = 0; n < 4; ++n) bv[n] = bias[gc0 + n * 16];
#pragma unroll
    for (int m = 0; m < 8; ++m)
#pragma unroll
        for (int j = 0; j < 4; ++j) {
            float* crow = C + (size_t)(gr0 + m * 16 + q * 4 + j) * N_DIM + gc0;
#pragma unroll
            for (int n = 0; n < 4; ++n)
                crow[n * 16] = acc[m][n][j] + bv[n];
        }
}

// ---------- naive fallback (only if ws too small)
__global__ void k_naive(const float* __restrict__ x, const int* __restrict__ qw,
                        const float* __restrict__ scales, const float* __restrict__ bias,
                        const float* __restrict__ lut, float* __restrict__ y) {
    long t = (long)blockIdx.x * blockDim.x + threadIdx.x;
    if (t >= (long)M_DIM * N_DIM) return;
    int m = (int)(t / N_DIM), n = (int)(t % N_DIM);
    float acc = 0.f;
    for (int k = 0; k < K_DIM; k += 2) {
        int b = qw[n * (K_DIM / 2) + (k >> 1)];
        float s = scales[n * 32 + (k >> 7)];
        acc += x[(size_t)m * K_DIM + k]     * lut[b & 15]        * s;
        acc += x[(size_t)m * K_DIM + k + 1] * lut[(b >> 4) & 15] * s;
    }
    y[t] = acc + bias[n];
}

extern "C" void kernel_launch(void* const* d_in, const int* in_sizes, int n_in,
                              void* d_out, int out_size, void* d_ws, size_t ws_size,
                              hipStream_t stream) {
    const float* x      = (const float*)d_in[0];
    const int*   qw     = (const int*)d_in[1];
    const float* scales = (const float*)d_in[2];
    const float* bias   = (const float*)d_in[3];
    const float* lut    = (const float*)d_in[5];
    float* y = (float*)d_out;

    const size_t wbBytes = (size_t)N_DIM * K_DIM * 2;   // 32 MiB
    const size_t xbBytes = (size_t)M_DIM * K_DIM * 2;   // 64 MiB
    if (ws_size < wbBytes + xbBytes) {
        long total = (long)M_DIM * N_DIM;
        k_naive<<<(int)((total + 255) / 256), 256, 0, stream>>>(x, qw, scales, bias, lut, y);
        return;
    }
    __hip_bfloat16* Wb = (__hip_bfloat16*)d_ws;
    __hip_bfloat16* Xb = (__hip_bfloat16*)((char*)d_ws + wbBytes);

    k_prep<<<DQ_BLOCKS + CVT_BLOCKS, 256, 0, stream>>>(
        (const int4*)qw, scales, lut, (uint4*)Wb, (const float4*)x, (uint4*)Xb);
    dim3 grid(N_DIM / 256, M_DIM / 256);
    k_gemm<<<grid, 512, 0, stream>>>(Xb, Wb, bias, y);
}

// Round 15
// 283.267 us; speedup vs baseline: 1.0261x; 1.0261x over previous
//
#include <hip/hip_runtime.h>
#include <hip/hip_bf16.h>
#include <stdint.h>

#define M_DIM 8192   // B*S
#define K_DIM 4096   // IN
#define N_DIM 4096   // OUT
#define NPIECE (K_DIM / 32)   // 128 K-pieces of 32

#define DQ_BLOCKS 8192    // N*(K/2)/4/256
#define CVT_BLOCKS 16384  // M*K/8/256

typedef __bf16 bf16x8v __attribute__((ext_vector_type(8)));
typedef float f32x4 __attribute__((ext_vector_type(4)));

__device__ __forceinline__ unsigned short f2bf(float f) {
    unsigned int u = __builtin_bit_cast(unsigned int, f);
    u += 0x7FFFu + ((u >> 16) & 1u);   // round-to-nearest-even
    return (unsigned short)(u >> 16);
}

// ---------- prep: blocks [0,DQ_BLOCKS) dequant qweight -> Wb; rest cvt x -> Xb
__global__ void k_prep(const int4* __restrict__ qw4,
                       const float* __restrict__ scales,
                       const float* __restrict__ lut,
                       uint4* __restrict__ wb4,
                       const float4* __restrict__ x4,
                       uint4* __restrict__ xb4) {
    if (blockIdx.x < DQ_BLOCKS) {
        __shared__ float sl[16];
        if (threadIdx.x < 16) sl[threadIdx.x] = lut[threadIdx.x];
        __syncthreads();
        int t = blockIdx.x * blockDim.x + threadIdx.x;   // N*(K/2)/4 threads
        int4 q = qw4[t];
        int o = t >> 9;                   // row (512 int4 per row)
        int col0 = (t & 511) << 3;        // first of 8 output cols
        float s = scales[(o << 5) + (col0 >> 7)];   // GS=128
        int v[4] = {q.x, q.y, q.z, q.w};
        unsigned int pk[4];
#pragma unroll
        for (int j = 0; j < 4; ++j) {
            float w0 = sl[v[j] & 15] * s;          // low nibble first
            float w1 = sl[(v[j] >> 4) & 15] * s;
            pk[j] = (unsigned int)f2bf(w0) | ((unsigned int)f2bf(w1) << 16);
        }
        uint4 rr; rr.x = pk[0]; rr.y = pk[1]; rr.z = pk[2]; rr.w = pk[3];
        wb4[t] = rr;
    } else {
        int t = (blockIdx.x - DQ_BLOCKS) * blockDim.x + threadIdx.x;   // M*K/8 threads
        float4 a = x4[2 * t], b = x4[2 * t + 1];
        uint4 o;
        o.x = (unsigned int)f2bf(a.x) | ((unsigned int)f2bf(a.y) << 16);
        o.y = (unsigned int)f2bf(a.z) | ((unsigned int)f2bf(a.w) << 16);
        o.z = (unsigned int)f2bf(b.x) | ((unsigned int)f2bf(b.y) << 16);
        o.w = (unsigned int)f2bf(b.z) | ((unsigned int)f2bf(b.w) << 16);
        xb4[t] = o;
    }
}

#define GLL16(SRC, DST)                                                              \
    __builtin_amdgcn_global_load_lds((__attribute__((address_space(1))) void*)(SRC), \
                                     (__attribute__((address_space(3))) void*)(DST), \
                                     16, 0, 0)

// ---------- GEMM: C[M][N] = Xb[M][K] * Wb[N][K]^T + bias
// FINAL: round-4/11 verified structure (best measured across 14 rounds:
// k_gemm 238-240 us steady, MfmaUtil ~55-57%, 0 bank conflicts).
// 256x256 tile, 8 waves (2Mx4N), K in 32-wide pieces, 4 LDS slots round-robin,
// register-fragment pipeline one half-piece ahead, ONE barrier per piece,
// counted vmcnt(4) boundaries, XOR-swizzled LDS (granule ^= (row>>1)&3).
// Ablated and rejected: 8-phase m201 port (-5%), 32x32x16 frags (-12%, conflicts),
// 2-indep-blocks/CU (-13/-18%), BK=64 merge (race), 5-slot 2-piece epoch (-3%),
// deeper vmcnt(8) prefetch (-10%), stage-first reorder (-1%).
__global__ __launch_bounds__(512, 2) void k_gemm(const __hip_bfloat16* __restrict__ A,
                                                 const __hip_bfloat16* __restrict__ Bw,
                                                 const float* __restrict__ bias,
                                                 float* __restrict__ C) {
    // slot: A piece [256 rows][32 K] bf16 (16KB) then B piece (16KB)
    __shared__ __align__(16) char lds[4][32768];   // 128 KiB

    const int tid  = threadIdx.x;
    const int lane = tid & 63;
    const int wave = tid >> 6;
    const int wm = wave >> 2;      // 0..1 -> M half
    const int wn = wave & 3;       // 0..3 -> N quarter
    const int bm = blockIdx.y, bn = blockIdx.x;

    f32x4 acc[8][4];
    const f32x4 z = {0.f, 0.f, 0.f, 0.f};
#pragma unroll
    for (int i = 0; i < 8; ++i)
#pragma unroll
        for (int j = 0; j < 4; ++j) acc[i][j] = z;

    // ---- staging addresses (pre-swizzled per-lane global source, linear LDS dest)
    const int trow = tid >> 2;                 // 0..127
    const int sg   = (tid & 3) ^ ((trow >> 1) & 3);   // swizzled source granule
    const char* aSrc = (const char*)A  + ((size_t)(bm * 256 + trow) * K_DIM) * 2 + sg * 16;
    const char* bSrc = (const char*)Bw + ((size_t)(bn * 256 + trow) * K_DIM) * 2 + sg * 16;
    const size_t hop = (size_t)128 * K_DIM * 2;   // +128 rows (second issue)
    const int woff = wave * 1024;                 // wave-uniform LDS dest base offset

    // ---- ds_read addresses (swizzled, verified zero-conflict)
    const int r   = lane & 15;
    const int kq  = lane >> 4;                  // K granule wanted
    const int gsw = kq ^ ((r >> 1) & 3);        // swizzled granule
    const int aOff = (wm * 128 + r) * 64 + gsw * 16;           // + m*1024
    const int bOff = 16384 + (wn * 64 + r) * 64 + gsw * 16;    // + n*1024

    bf16x8v aC[4], aN[4], bX[4], bY[4];

#define STAGE_A(P)                                                           \
    do {                                                                     \
        char* d_ = (char*)lds[(P) & 3];                                      \
        const size_t ko_ = (size_t)(P) * 64;                                 \
        GLL16(aSrc + ko_,       d_ + 0    + woff);                           \
        GLL16(aSrc + hop + ko_, d_ + 8192 + woff);                           \
    } while (0)
#define STAGE_B(P)                                                           \
    do {                                                                     \
        char* d_ = (char*)lds[(P) & 3];                                      \
        const size_t ko_ = (size_t)(P) * 64;                                 \
        GLL16(bSrc + ko_,       d_ + 16384 + woff);                          \
        GLL16(bSrc + hop + ko_, d_ + 24576 + woff);                          \
    } while (0)

    // Piece body. BCUR = this piece's B frags (loaded last piece); BNXT gets next
    // piece's B. aC holds A0-3(P) (loaded last piece), aN gets A4-7(P) in HP0 and
    // is consumed in HP1; aC is refilled with A0-3(P+1) in HP1.
#define PIECE_BODY(P, BCUR, BNXT, GLLON, RDNEXT, WAITSTR)                                              \
    do {                                                                                               \
        const char* slC_ = (const char*)&lds[0][0] + (((P) & 3) << 15);                                \
        const char* slN_ = (const char*)&lds[0][0] + ((((P) + 1) & 3) << 15);                          \
        /* HP0: issue reads A4-7(P); issue stage(P+3); MFMA m0-3 on prior-loaded regs */               \
        _Pragma("unroll") for (int m = 0; m < 4; ++m)                                                  \
            aN[m] = *(const bf16x8v*)(slC_ + aOff + (m + 4) * 1024);                                   \
        if (GLLON) { STAGE_A((P) + 3); STAGE_B((P) + 3); }                                             \
        asm volatile("" ::: "memory");                                                                 \
        __builtin_amdgcn_s_setprio(1);                                                                 \
        _Pragma("unroll") for (int m = 0; m < 4; ++m)                                                  \
            _Pragma("unroll") for (int n = 0; n < 4; ++n)                                              \
                acc[m][n] = __builtin_amdgcn_mfma_f32_16x16x32_bf16(aC[m], BCUR[n], acc[m][n], 0, 0, 0); \
        __builtin_amdgcn_s_setprio(0);                                                                 \
        /* HP1: issue reads A0-3(P+1)->aC, B(P+1)->BNXT; MFMA m4-7 */                                  \
        if (RDNEXT) {                                                                                  \
            _Pragma("unroll") for (int m = 0; m < 4; ++m)                                              \
                aC[m] = *(const bf16x8v*)(slN_ + aOff + m * 1024);                                     \
            _Pragma("unroll") for (int n = 0; n < 4; ++n)                                              \
                BNXT[n] = *(const bf16x8v*)(slN_ + bOff + n * 1024);                                   \
        }                                                                                              \
        asm volatile("" ::: "memory");                                                                 \
        __builtin_amdgcn_s_setprio(1);                                                                 \
        _Pragma("unroll") for (int m = 0; m < 4; ++m)                                                  \
            _Pragma("unroll") for (int n = 0; n < 4; ++n)                                              \
                acc[m + 4][n] =                                                                        \
                    __builtin_amdgcn_mfma_f32_16x16x32_bf16(aN[m], BCUR[n], acc[m + 4][n], 0, 0, 0);   \
        __builtin_amdgcn_s_setprio(0);                                                                 \
        asm volatile(WAITSTR ::: "memory");                                                            \
        __builtin_amdgcn_s_barrier();                                                                  \
        asm volatile("" ::: "memory");                                                                 \
    } while (0)

    // ---- prologue: stage pieces 0,1,2; wait until stage(0),(1) landed; preload piece-0 regs
    STAGE_A(0); STAGE_B(0);
    STAGE_A(1); STAGE_B(1);
    STAGE_A(2); STAGE_B(2);
    asm volatile("s_waitcnt vmcnt(4)" ::: "memory");   // stages 0,1 landed; 2 in flight
    __builtin_amdgcn_s_barrier();
    asm volatile("" ::: "memory");
#pragma unroll
    for (int m = 0; m < 4; ++m)
        aC[m] = *(const bf16x8v*)((const char*)&lds[0][0] + aOff + m * 1024);
#pragma unroll
    for (int n = 0; n < 4; ++n)
        bX[n] = *(const bf16x8v*)((const char*)&lds[0][0] + bOff + n * 1024);

    // ---- main loop: pieces 0..123 (b-roles alternate by parity)
    for (int p = 0; p < NPIECE - 4; p += 2) {
        PIECE_BODY(p,     bX, bY, 1, 1, "s_waitcnt vmcnt(4)");
        PIECE_BODY(p + 1, bY, bX, 1, 1, "s_waitcnt vmcnt(4)");
    }
    // ---- tail: pieces 124..127 (stage(127) issued at 124; then drain)
    PIECE_BODY(124, bX, bY, 1, 1, "s_waitcnt vmcnt(4)");
    PIECE_BODY(125, bY, bX, 0, 1, "s_waitcnt vmcnt(0)");
    PIECE_BODY(126, bX, bY, 0, 1, "s_nop 0");
    PIECE_BODY(127, bY, bX, 0, 0, "s_nop 0");

#undef PIECE_BODY
#undef STAGE_A
#undef STAGE_B

    // ---- epilogue: C/D layout col=lane&15, row=(lane>>4)*4+j
    const int q   = lane >> 4;
    const int gr0 = bm * 256 + wm * 128;
    const int gc0 = bn * 256 + wn * 64 + r;
    float bv[4];
#pragma unroll
    for (int n = 0; n < 4; ++n) bv[n] = bias[gc0 + n * 16];
#pragma unroll
    for (int m = 0; m < 8; ++m)
#pragma unroll
        for (int j = 0; j < 4; ++j) {
            float* crow = C + (size_t)(gr0 + m * 16 + q * 4 + j) * N_DIM + gc0;
#pragma unroll
            for (int n = 0; n < 4; ++n)
                crow[n * 16] = acc[m][n][j] + bv[n];
        }
}

// ---------- naive fallback (only if ws too small)
__global__ void k_naive(const float* __restrict__ x, const int* __restrict__ qw,
                        const float* __restrict__ scales, const float* __restrict__ bias,
                        const float* __restrict__ lut, float* __restrict__ y) {
    long t = (long)blockIdx.x * blockDim.x + threadIdx.x;
    if (t >= (long)M_DIM * N_DIM) return;
    int m = (int)(t / N_DIM), n = (int)(t % N_DIM);
    float acc = 0.f;
    for (int k = 0; k < K_DIM; k += 2) {
        int b = qw[n * (K_DIM / 2) + (k >> 1)];
        float s = scales[n * 32 + (k >> 7)];
        acc += x[(size_t)m * K_DIM + k]     * lut[b & 15]        * s;
        acc += x[(size_t)m * K_DIM + k + 1] * lut[(b >> 4) & 15] * s;
    }
    y[t] = acc + bias[n];
}

extern "C" void kernel_launch(void* const* d_in, const int* in_sizes, int n_in,
                              void* d_out, int out_size, void* d_ws, size_t ws_size,
                              hipStream_t stream) {
    const float* x      = (const float*)d_in[0];
    const int*   qw     = (const int*)d_in[1];
    const float* scales = (const float*)d_in[2];
    const float* bias   = (const float*)d_in[3];
    const float* lut    = (const float*)d_in[5];
    float* y = (float*)d_out;

    const size_t wbBytes = (size_t)N_DIM * K_DIM * 2;   // 32 MiB
    const size_t xbBytes = (size_t)M_DIM * K_DIM * 2;   // 64 MiB
    if (ws_size < wbBytes + xbBytes) {
        long total = (long)M_DIM * N_DIM;
        k_naive<<<(int)((total + 255) / 256), 256, 0, stream>>>(x, qw, scales, bias, lut, y);
        return;
    }
    __hip_bfloat16* Wb = (__hip_bfloat16*)d_ws;
    __hip_bfloat16* Xb = (__hip_bfloat16*)((char*)d_ws + wbBytes);

    k_prep<<<DQ_BLOCKS + CVT_BLOCKS, 256, 0, stream>>>(
        (const int4*)qw, scales, lut, (uint4*)Wb, (const float4*)x, (uint4*)Xb);
    dim3 grid(N_DIM / 256, M_DIM / 256);
    k_gemm<<<grid, 512, 0, stream>>>(Xb, Wb, bias, y);
}